// Round 1
// baseline (6066.417 us; speedup 1.0000x reference)
//
#include <hip/hip_runtime.h>

#define NEG_SLOPE 0.2f
#define NPB 8

// K1: h = x @ W1  [N,128]; asrc[n,h] = <h[n,h,:], att_src[h,:]>; adst likewise.
__global__ __launch_bounds__(128) void k_feat1(
    const float* __restrict__ x, const float* __restrict__ W1,
    const float* __restrict__ att_src, const float* __restrict__ att_dst,
    float* __restrict__ h, float* __restrict__ asrc, float* __restrict__ adst, int N)
{
    int n = blockIdx.x;
    int c = threadIdx.x;            // 0..127, flat channel = head*32+cc
    const float* xr = x + (size_t)n * 8;
    float acc = 0.f;
    #pragma unroll
    for (int k = 0; k < 8; k++) acc += xr[k] * W1[k * 128 + c];
    h[(size_t)n * 128 + c] = acc;
    float ps = acc * att_src[c];    // att flat index == c
    float pd = acc * att_dst[c];
    #pragma unroll
    for (int off = 16; off >= 1; off >>= 1) {
        ps += __shfl_xor(ps, off, 64);
        pd += __shfl_xor(pd, off, 64);
    }
    if ((c & 31) == 0) {
        int head = c >> 5;
        asrc[n * 4 + head] = ps;
        adst[n * 4 + head] = pd;
    }
}

// K2/K5: per-edge softmax-weighted aggregation (32 threads per edge, 4 ch each).
__global__ __launch_bounds__(256) void k_edge(
    const int* __restrict__ ei, int E, int EN,
    const float* __restrict__ h,
    const float* __restrict__ asrc, const float* __restrict__ adst,
    float* __restrict__ acc, float* __restrict__ denom)
{
    long long t = (long long)blockIdx.x * 256 + threadIdx.x;
    int e = (int)(t >> 5);
    if (e >= EN) return;
    int lane = (int)(t & 31);
    int src, dst;
    if (e < E) { src = ei[e]; dst = ei[E + e]; }
    else       { src = dst = e - E; }          // self-loop
    int head = lane >> 3;
    float a = asrc[src * 4 + head] + adst[dst * 4 + head];
    float lr = a > 0.f ? a : NEG_SLOPE * a;
    float w = expf(lr);                        // no max-subtract needed: |lr| small
    if ((lane & 7) == 0) atomicAdd(&denom[dst * 4 + head], w);
    const float4 hv = *reinterpret_cast<const float4*>(h + (size_t)src * 128 + lane * 4);
    float* ap = acc + (size_t)dst * 128 + lane * 4;
    atomicAdd(ap + 0, w * hv.x);
    atomicAdd(ap + 1, w * hv.y);
    atomicAdd(ap + 2, w * hv.z);
    atomicAdd(ap + 3, w * hv.w);
}

// K3: out1 = relu(acc/denom + bias1), in place.
__global__ __launch_bounds__(256) void k_fin1(
    float* __restrict__ acc, const float* __restrict__ denom,
    const float* __restrict__ bias, int N)
{
    int i = blockIdx.x * 256 + threadIdx.x;
    if (i >= N * 128) return;
    int n = i >> 7, c = i & 127;
    float v = acc[i] / denom[n * 4 + (c >> 5)] + bias[c];
    acc[i] = v > 0.f ? v : 0.f;
}

// K4: h2 = out1 @ W2 (128x128) + asrc2/adst2. NPB nodes per block share W2 reads.
__global__ __launch_bounds__(128) void k_feat2(
    const float* __restrict__ in, const float* __restrict__ W2,
    const float* __restrict__ att_src, const float* __restrict__ att_dst,
    float* __restrict__ h, float* __restrict__ asrc, float* __restrict__ adst, int N)
{
    __shared__ float rows[NPB][128];
    int n0 = blockIdx.x * NPB;
    int c = threadIdx.x;
    #pragma unroll
    for (int j = 0; j < NPB; j++) {
        int n = n0 + j;
        rows[j][c] = (n < N) ? in[(size_t)n * 128 + c] : 0.f;
    }
    __syncthreads();
    float acc[NPB];
    #pragma unroll
    for (int j = 0; j < NPB; j++) acc[j] = 0.f;
    for (int k = 0; k < 128; k++) {
        float wv = W2[k * 128 + c];
        #pragma unroll
        for (int j = 0; j < NPB; j++) acc[j] += rows[j][k] * wv;
    }
    float as = att_src[c], ad = att_dst[c];
    for (int j = 0; j < NPB; j++) {
        int n = n0 + j;
        if (n >= N) break;                      // block-uniform branch
        h[(size_t)n * 128 + c] = acc[j];
        float ps = acc[j] * as, pd = acc[j] * ad;
        #pragma unroll
        for (int off = 16; off >= 1; off >>= 1) {
            ps += __shfl_xor(ps, off, 64);
            pd += __shfl_xor(pd, off, 64);
        }
        if ((c & 31) == 0) {
            int head = c >> 5;
            asrc[n * 4 + head] = ps;
            adst[n * 4 + head] = pd;
        }
    }
}

// K6: out[n] = <relu(mean_heads(acc/denom) + bias2), W_lin> + b_lin. One wave/node.
__global__ __launch_bounds__(256) void k_out(
    const float* __restrict__ acc, const float* __restrict__ denom,
    const float* __restrict__ bias2, const float* __restrict__ Wlin,
    const float* __restrict__ blin, float* __restrict__ out, int N)
{
    int wave = (blockIdx.x * 256 + threadIdx.x) >> 6;
    if (wave >= N) return;
    int lane = threadIdx.x & 63;
    int n = wave;
    int cc = lane & 31;
    int h0 = lane >> 5;                         // lanes 0-31: heads {0,2}; 32-63: {1,3}
    float inv0 = 1.f / denom[n * 4 + h0];
    float inv1 = 1.f / denom[n * 4 + h0 + 2];
    float v = acc[(size_t)n * 128 + h0 * 32 + cc] * inv0
            + acc[(size_t)n * 128 + (h0 + 2) * 32 + cc] * inv1;
    v += __shfl_xor(v, 32, 64);                 // combine head pairs
    float m = 0.25f * v + bias2[cc];
    float y = m > 0.f ? m : 0.f;
    float t = y * Wlin[cc];
    #pragma unroll
    for (int off = 16; off >= 1; off >>= 1) t += __shfl_xor(t, off, 64);
    if (lane == 0) out[n] = t + blin[0];
}

extern "C" void kernel_launch(void* const* d_in, const int* in_sizes, int n_in,
                              void* d_out, int out_size, void* d_ws, size_t ws_size,
                              hipStream_t stream)
{
    const float* x   = (const float*)d_in[0];
    const int*   ei  = (const int*)  d_in[1];
    const float* W1  = (const float*)d_in[2];
    const float* as1 = (const float*)d_in[3];
    const float* ad1 = (const float*)d_in[4];
    const float* b1  = (const float*)d_in[5];
    const float* W2  = (const float*)d_in[6];
    const float* as2 = (const float*)d_in[7];
    const float* ad2 = (const float*)d_in[8];
    const float* b2  = (const float*)d_in[9];
    const float* Wl  = (const float*)d_in[10];
    const float* bl  = (const float*)d_in[11];
    float* out = (float*)d_out;

    int N  = in_sizes[0] / 8;
    int E  = in_sizes[1] / 2;
    int EN = E + N;

    float* ws    = (float*)d_ws;
    float* A     = ws;                          // N*128: h1, then h2
    float* B     = A + (size_t)N * 128;         // N*128: acc1/out1, then acc2
    float* denom = B + (size_t)N * 128;         // N*4
    float* asrc  = denom + (size_t)N * 4;       // N*4
    float* adst  = asrc + (size_t)N * 4;        // N*4

    int eb = (int)(((long long)EN * 32 + 255) / 256);

    // Layer 1
    hipMemsetAsync(B, 0, (size_t)N * 132 * sizeof(float), stream);   // acc + denom
    k_feat1<<<N, 128, 0, stream>>>(x, W1, as1, ad1, A, asrc, adst, N);
    k_edge<<<eb, 256, 0, stream>>>(ei, E, EN, A, asrc, adst, B, denom);
    k_fin1<<<(N * 128 + 255) / 256, 256, 0, stream>>>(B, denom, b1, N);

    // Layer 2
    k_feat2<<<(N + NPB - 1) / NPB, 128, 0, stream>>>(B, W2, as2, ad2, A, asrc, adst, N);
    hipMemsetAsync(B, 0, (size_t)N * 132 * sizeof(float), stream);   // acc + denom
    k_edge<<<eb, 256, 0, stream>>>(ei, E, EN, A, asrc, adst, B, denom);
    k_out<<<(N + 3) / 4, 256, 0, stream>>>(B, denom, b2, Wl, bl, out, N);
}

// Round 2
// 982.191 us; speedup vs baseline: 6.1764x; 6.1764x over previous
//
#include <hip/hip_runtime.h>

#define NEG_SLOPE 0.2f
#define NPB 8

// K1: h = x @ W1  [N,128]; asrc[n,h] = <h[n,h,:], att_src[h,:]>; adst likewise.
__global__ __launch_bounds__(128) void k_feat1(
    const float* __restrict__ x, const float* __restrict__ W1,
    const float* __restrict__ att_src, const float* __restrict__ att_dst,
    float* __restrict__ h, float* __restrict__ asrc, float* __restrict__ adst, int N)
{
    int n = blockIdx.x;
    int c = threadIdx.x;            // 0..127, flat channel = head*32+cc
    const float* xr = x + (size_t)n * 8;
    float acc = 0.f;
    #pragma unroll
    for (int k = 0; k < 8; k++) acc += xr[k] * W1[k * 128 + c];
    h[(size_t)n * 128 + c] = acc;
    float ps = acc * att_src[c];
    float pd = acc * att_dst[c];
    #pragma unroll
    for (int off = 16; off >= 1; off >>= 1) {
        ps += __shfl_xor(ps, off, 64);
        pd += __shfl_xor(pd, off, 64);
    }
    if ((c & 31) == 0) {
        int head = c >> 5;
        asrc[n * 4 + head] = ps;
        adst[n * 4 + head] = pd;
    }
}

// CSR build step 1: in-degree histogram (self-loops included).
__global__ __launch_bounds__(256) void k_hist(
    const int* __restrict__ ei, int E, int EN, int* __restrict__ cnt)
{
    int e = blockIdx.x * 256 + threadIdx.x;
    if (e >= EN) return;
    int dst = (e < E) ? ei[E + e] : (e - E);
    atomicAdd(&cnt[dst], 1);
}

// CSR build step 2: single-block exclusive scan of cnt[N] -> rowptr[N+1],
// and init cursor (aliased onto cnt) to the row starts.
__global__ __launch_bounds__(1024) void k_scan(
    int* __restrict__ cnt /* in: counts, out: cursor */,
    int* __restrict__ rowptr, int N)
{
    __shared__ int sums[1024];
    int t = threadIdx.x;
    int chunk = (N + 1023) >> 10;
    int lo = t * chunk;
    int hi = lo + chunk; if (hi > N) hi = N; if (lo > N) lo = N;
    int s = 0;
    for (int i = lo; i < hi; i++) s += cnt[i];
    sums[t] = s;
    __syncthreads();
    for (int off = 1; off < 1024; off <<= 1) {
        int u = (t >= off) ? sums[t - off] : 0;
        __syncthreads();
        sums[t] += u;
        __syncthreads();
    }
    int run = sums[t] - s;          // exclusive prefix
    for (int i = lo; i < hi; i++) {
        int cv = cnt[i];            // read before overwrite (same thread owns i)
        rowptr[i] = run;
        cnt[i] = run;               // cursor init
        run += cv;
    }
    if (t == 1023) rowptr[N] = run; // total = E + N
}

// CSR build step 3: scatter src ids into dst-sorted order.
__global__ __launch_bounds__(256) void k_scatter(
    const int* __restrict__ ei, int E, int EN,
    int* __restrict__ cursor, int* __restrict__ esrc)
{
    int e = blockIdx.x * 256 + threadIdx.x;
    if (e >= EN) return;
    int src, dst;
    if (e < E) { src = ei[e]; dst = ei[E + e]; }
    else       { src = dst = e - E; }
    int pos = atomicAdd(&cursor[dst], 1);
    esrc[pos] = src;
}

// Core: one wave per dst node. Lane owns channels {lane, lane+64} ->
// heads {lane>>5, (lane>>5)+2}. Accumulate weighted messages + denoms in regs.
__device__ __forceinline__ void agg_core(
    int n, int lane,
    const int* __restrict__ rowptr, const int* __restrict__ esrc,
    const float* __restrict__ h, const float* __restrict__ asrc,
    const float* __restrict__ adst,
    float& acc0, float& acc1, float& d0, float& d1)
{
    int h0 = lane >> 5;
    float ad0 = adst[n * 4 + h0];
    float ad1 = adst[n * 4 + h0 + 2];
    acc0 = acc1 = d0 = d1 = 0.f;
    int beg = rowptr[n], end = rowptr[n + 1];
    for (int j = beg; j < end; j++) {
        int src = esrc[j];                          // wave-uniform broadcast
        float as0 = asrc[src * 4 + h0];
        float as1 = asrc[src * 4 + h0 + 2];
        float a0 = as0 + ad0; a0 = a0 > 0.f ? a0 : NEG_SLOPE * a0;
        float a1 = as1 + ad1; a1 = a1 > 0.f ? a1 : NEG_SLOPE * a1;
        float w0 = __expf(a0), w1 = __expf(a1);     // |a| small: no max-sub needed
        const float* hp = h + (size_t)src * 128;
        acc0 = fmaf(w0, hp[lane], acc0);
        acc1 = fmaf(w1, hp[lane + 64], acc1);
        d0 += w0; d1 += w1;
    }
}

// Layer-1 aggregate + fused epilogue: out = relu(acc/denom + bias1).
__global__ __launch_bounds__(256) void k_agg1(
    const int* __restrict__ rowptr, const int* __restrict__ esrc,
    const float* __restrict__ h, const float* __restrict__ asrc,
    const float* __restrict__ adst, const float* __restrict__ bias,
    float* __restrict__ outp, int N)
{
    int wave = (blockIdx.x * 256 + threadIdx.x) >> 6;
    if (wave >= N) return;
    int lane = threadIdx.x & 63;
    float acc0, acc1, d0, d1;
    agg_core(wave, lane, rowptr, esrc, h, asrc, adst, acc0, acc1, d0, d1);
    float v0 = acc0 / d0 + bias[lane];
    float v1 = acc1 / d1 + bias[lane + 64];
    outp[(size_t)wave * 128 + lane]      = v0 > 0.f ? v0 : 0.f;
    outp[(size_t)wave * 128 + 64 + lane] = v1 > 0.f ? v1 : 0.f;
}

// Layer-2 aggregate + fused final: mean over heads, +bias2, relu, dot W_lin.
__global__ __launch_bounds__(256) void k_agg2(
    const int* __restrict__ rowptr, const int* __restrict__ esrc,
    const float* __restrict__ h, const float* __restrict__ asrc,
    const float* __restrict__ adst, const float* __restrict__ bias2,
    const float* __restrict__ Wlin, const float* __restrict__ blin,
    float* __restrict__ out, int N)
{
    int wave = (blockIdx.x * 256 + threadIdx.x) >> 6;
    if (wave >= N) return;
    int lane = threadIdx.x & 63;
    float acc0, acc1, d0, d1;
    agg_core(wave, lane, rowptr, esrc, h, asrc, adst, acc0, acc1, d0, d1);
    float v = acc0 / d0 + acc1 / d1;    // heads h0 and h0+2 of channel cc
    v += __shfl_xor(v, 32, 64);         // + heads from other lane half
    int cc = lane & 31;
    float m = 0.25f * v + bias2[cc];
    float y = m > 0.f ? m : 0.f;
    float t = y * Wlin[cc];
    #pragma unroll
    for (int off = 16; off >= 1; off >>= 1) t += __shfl_xor(t, off, 64);
    if (lane == 0) out[wave] = t + blin[0];
}

// h2 = out1 @ W2 (128x128) + asrc2/adst2. NPB nodes per block share W2 reads.
__global__ __launch_bounds__(128) void k_feat2(
    const float* __restrict__ in, const float* __restrict__ W2,
    const float* __restrict__ att_src, const float* __restrict__ att_dst,
    float* __restrict__ h, float* __restrict__ asrc, float* __restrict__ adst, int N)
{
    __shared__ float rows[NPB][128];
    int n0 = blockIdx.x * NPB;
    int c = threadIdx.x;
    #pragma unroll
    for (int j = 0; j < NPB; j++) {
        int n = n0 + j;
        rows[j][c] = (n < N) ? in[(size_t)n * 128 + c] : 0.f;
    }
    __syncthreads();
    float acc[NPB];
    #pragma unroll
    for (int j = 0; j < NPB; j++) acc[j] = 0.f;
    for (int k = 0; k < 128; k++) {
        float wv = W2[k * 128 + c];
        #pragma unroll
        for (int j = 0; j < NPB; j++) acc[j] += rows[j][k] * wv;
    }
    float as = att_src[c], ad = att_dst[c];
    for (int j = 0; j < NPB; j++) {
        int n = n0 + j;
        if (n >= N) break;
        h[(size_t)n * 128 + c] = acc[j];
        float ps = acc[j] * as, pd = acc[j] * ad;
        #pragma unroll
        for (int off = 16; off >= 1; off >>= 1) {
            ps += __shfl_xor(ps, off, 64);
            pd += __shfl_xor(pd, off, 64);
        }
        if ((c & 31) == 0) {
            int head = c >> 5;
            asrc[n * 4 + head] = ps;
            adst[n * 4 + head] = pd;
        }
    }
}

extern "C" void kernel_launch(void* const* d_in, const int* in_sizes, int n_in,
                              void* d_out, int out_size, void* d_ws, size_t ws_size,
                              hipStream_t stream)
{
    const float* x   = (const float*)d_in[0];
    const int*   ei  = (const int*)  d_in[1];
    const float* W1  = (const float*)d_in[2];
    const float* as1 = (const float*)d_in[3];
    const float* ad1 = (const float*)d_in[4];
    const float* b1  = (const float*)d_in[5];
    const float* W2  = (const float*)d_in[6];
    const float* as2 = (const float*)d_in[7];
    const float* ad2 = (const float*)d_in[8];
    const float* b2  = (const float*)d_in[9];
    const float* Wl  = (const float*)d_in[10];
    const float* bl  = (const float*)d_in[11];
    float* out = (float*)d_out;

    int N  = in_sizes[0] / 8;
    int E  = in_sizes[1] / 2;
    int EN = E + N;

    float* ws    = (float*)d_ws;
    float* A     = ws;                          // N*128: h1, then h2
    float* B     = A + (size_t)N * 128;         // N*128: out1 (= feat2 input)
    float* asrc  = B + (size_t)N * 128;         // N*4
    float* adst  = asrc + (size_t)N * 4;        // N*4
    int* cnt     = (int*)(adst + (size_t)N * 4);// N  (counts, then cursor)
    int* rowptr  = cnt + N;                     // N+1
    int* esrc    = rowptr + N + 1;              // EN

    int eb = (EN + 255) / 256;
    int nb = (N + 3) / 4;                       // 4 waves/block, 1 wave/node

    // CSR build (shared by both layers)
    hipMemsetAsync(cnt, 0, (size_t)N * sizeof(int), stream);
    k_hist<<<eb, 256, 0, stream>>>(ei, E, EN, cnt);
    k_scan<<<1, 1024, 0, stream>>>(cnt, rowptr, N);
    k_scatter<<<eb, 256, 0, stream>>>(ei, E, EN, cnt, esrc);

    // Layer 1
    k_feat1<<<N, 128, 0, stream>>>(x, W1, as1, ad1, A, asrc, adst, N);
    k_agg1<<<nb, 256, 0, stream>>>(rowptr, esrc, A, asrc, adst, b1, B, N);

    // Layer 2
    k_feat2<<<(N + NPB - 1) / NPB, 128, 0, stream>>>(B, W2, as2, ad2, A, asrc, adst, N);
    k_agg2<<<nb, 256, 0, stream>>>(rowptr, esrc, A, asrc, adst, b2, Wl, bl, out, N);
}

// Round 3
// 659.757 us; speedup vs baseline: 9.1949x; 1.4887x over previous
//
#include <hip/hip_runtime.h>

#define NEG_SLOPE 0.2f
#define NPB 8
#define SCAN_B 1024

// K1: h = x @ W1  [N,128]; asrc[n,h] = <h[n,h,:], att_src[h,:]>; adst likewise.
__global__ __launch_bounds__(128) void k_feat1(
    const float* __restrict__ x, const float* __restrict__ W1,
    const float* __restrict__ att_src, const float* __restrict__ att_dst,
    float* __restrict__ h, float* __restrict__ asrc, float* __restrict__ adst, int N)
{
    int n = blockIdx.x;
    int c = threadIdx.x;            // 0..127, flat channel = head*32+cc
    const float* xr = x + (size_t)n * 8;
    float acc = 0.f;
    #pragma unroll
    for (int k = 0; k < 8; k++) acc += xr[k] * W1[k * 128 + c];
    h[(size_t)n * 128 + c] = acc;
    float ps = acc * att_src[c];
    float pd = acc * att_dst[c];
    #pragma unroll
    for (int off = 16; off >= 1; off >>= 1) {
        ps += __shfl_xor(ps, off, 64);
        pd += __shfl_xor(pd, off, 64);
    }
    if ((c & 31) == 0) {
        int head = c >> 5;
        asrc[n * 4 + head] = ps;
        adst[n * 4 + head] = pd;
    }
}

// CSR build step 1: in-degree histogram (self-loops included).
__global__ __launch_bounds__(256) void k_hist(
    const int* __restrict__ ei, int E, int EN, int* __restrict__ cnt)
{
    int e = blockIdx.x * 256 + threadIdx.x;
    if (e >= EN) return;
    int dst = (e < E) ? ei[E + e] : (e - E);
    atomicAdd(&cnt[dst], 1);
}

// Scan phase A: per-1024-tile sums.
__global__ __launch_bounds__(SCAN_B) void k_scanA(
    const int* __restrict__ cnt, int* __restrict__ bsum, int N)
{
    __shared__ int red[SCAN_B];
    int t = threadIdx.x;
    int i = blockIdx.x * SCAN_B + t;
    red[t] = (i < N) ? cnt[i] : 0;
    __syncthreads();
    #pragma unroll
    for (int off = SCAN_B / 2; off > 0; off >>= 1) {
        if (t < off) red[t] += red[t + off];
        __syncthreads();
    }
    if (t == 0) bsum[blockIdx.x] = red[0];
}

// Scan phase B: exclusive scan of bsum[G] in one block (G <= 1024 here: G=ceil(N/1024)).
__global__ __launch_bounds__(SCAN_B) void k_scanB(int* __restrict__ bsum, int G)
{
    __shared__ int s[SCAN_B];
    int t = threadIdx.x;
    int v = (t < G) ? bsum[t] : 0;
    s[t] = v;
    __syncthreads();
    for (int off = 1; off < SCAN_B; off <<= 1) {
        int u = (t >= off) ? s[t - off] : 0;
        __syncthreads();
        s[t] += u;
        __syncthreads();
    }
    if (t < G) bsum[t] = s[t] - v;      // exclusive
}

// Scan phase C: intra-tile exclusive scan + block offset -> rowptr; cursor init
// in place over cnt (each thread reads its own cnt[i] before overwriting).
__global__ __launch_bounds__(SCAN_B) void k_scanC(
    int* __restrict__ cnt /* in: counts, out: cursor */,
    const int* __restrict__ bsum, int* __restrict__ rowptr, int N)
{
    __shared__ int s[SCAN_B];
    int t = threadIdx.x;
    int i = blockIdx.x * SCAN_B + t;
    int v = (i < N) ? cnt[i] : 0;
    s[t] = v;
    __syncthreads();
    for (int off = 1; off < SCAN_B; off <<= 1) {
        int u = (t >= off) ? s[t - off] : 0;
        __syncthreads();
        s[t] += u;
        __syncthreads();
    }
    int excl = s[t] - v + bsum[blockIdx.x];
    if (i < N) {
        rowptr[i] = excl;
        cnt[i] = excl;                  // cursor
        if (i == N - 1) rowptr[N] = excl + v;
    }
}

// CSR build step 3: scatter src ids into dst-sorted order.
__global__ __launch_bounds__(256) void k_scatter(
    const int* __restrict__ ei, int E, int EN,
    int* __restrict__ cursor, int* __restrict__ esrc)
{
    int e = blockIdx.x * 256 + threadIdx.x;
    if (e >= EN) return;
    int src, dst;
    if (e < E) { src = ei[e]; dst = ei[E + e]; }
    else       { src = dst = e - E; }
    int pos = atomicAdd(&cursor[dst], 1);
    esrc[pos] = src;
}

// Core: one wave per dst node. Lane owns channels {lane, lane+64} ->
// heads {lane>>5, (lane>>5)+2}. Accumulate weighted messages + denoms in regs.
__device__ __forceinline__ void agg_core(
    int n, int lane,
    const int* __restrict__ rowptr, const int* __restrict__ esrc,
    const float* __restrict__ h, const float* __restrict__ asrc,
    const float* __restrict__ adst,
    float& acc0, float& acc1, float& d0, float& d1)
{
    int h0 = lane >> 5;
    float ad0 = adst[n * 4 + h0];
    float ad1 = adst[n * 4 + h0 + 2];
    acc0 = acc1 = d0 = d1 = 0.f;
    int beg = rowptr[n], end = rowptr[n + 1];
    #pragma unroll 4
    for (int j = beg; j < end; j++) {
        int src = esrc[j];                          // wave-uniform
        float as0 = asrc[src * 4 + h0];
        float as1 = asrc[src * 4 + h0 + 2];
        float a0 = as0 + ad0; a0 = a0 > 0.f ? a0 : NEG_SLOPE * a0;
        float a1 = as1 + ad1; a1 = a1 > 0.f ? a1 : NEG_SLOPE * a1;
        float w0 = __expf(a0), w1 = __expf(a1);     // |a| small: no max-sub needed
        const float* hp = h + (size_t)src * 128;
        acc0 = fmaf(w0, hp[lane], acc0);
        acc1 = fmaf(w1, hp[lane + 64], acc1);
        d0 += w0; d1 += w1;
    }
}

// Layer-1 aggregate + fused epilogue: out = relu(acc/denom + bias1).
__global__ __launch_bounds__(256) void k_agg1(
    const int* __restrict__ rowptr, const int* __restrict__ esrc,
    const float* __restrict__ h, const float* __restrict__ asrc,
    const float* __restrict__ adst, const float* __restrict__ bias,
    float* __restrict__ outp, int N)
{
    int wave = (blockIdx.x * 256 + threadIdx.x) >> 6;
    if (wave >= N) return;
    int lane = threadIdx.x & 63;
    float acc0, acc1, d0, d1;
    agg_core(wave, lane, rowptr, esrc, h, asrc, adst, acc0, acc1, d0, d1);
    float v0 = acc0 / d0 + bias[lane];
    float v1 = acc1 / d1 + bias[lane + 64];
    outp[(size_t)wave * 128 + lane]      = v0 > 0.f ? v0 : 0.f;
    outp[(size_t)wave * 128 + 64 + lane] = v1 > 0.f ? v1 : 0.f;
}

// Layer-2 aggregate + fused final: mean over heads, +bias2, relu, dot W_lin.
__global__ __launch_bounds__(256) void k_agg2(
    const int* __restrict__ rowptr, const int* __restrict__ esrc,
    const float* __restrict__ h, const float* __restrict__ asrc,
    const float* __restrict__ adst, const float* __restrict__ bias2,
    const float* __restrict__ Wlin, const float* __restrict__ blin,
    float* __restrict__ out, int N)
{
    int wave = (blockIdx.x * 256 + threadIdx.x) >> 6;
    if (wave >= N) return;
    int lane = threadIdx.x & 63;
    float acc0, acc1, d0, d1;
    agg_core(wave, lane, rowptr, esrc, h, asrc, adst, acc0, acc1, d0, d1);
    float v = acc0 / d0 + acc1 / d1;    // heads h0 and h0+2 of channel cc
    v += __shfl_xor(v, 32, 64);         // + heads from other lane half
    int cc = lane & 31;
    float m = 0.25f * v + bias2[cc];
    float y = m > 0.f ? m : 0.f;
    float t = y * Wlin[cc];
    #pragma unroll
    for (int off = 16; off >= 1; off >>= 1) t += __shfl_xor(t, off, 64);
    if (lane == 0) out[wave] = t + blin[0];
}

// h2 = out1 @ W2 (128x128) + asrc2/adst2. NPB nodes per block share W2 reads.
__global__ __launch_bounds__(128) void k_feat2(
    const float* __restrict__ in, const float* __restrict__ W2,
    const float* __restrict__ att_src, const float* __restrict__ att_dst,
    float* __restrict__ h, float* __restrict__ asrc, float* __restrict__ adst, int N)
{
    __shared__ float rows[NPB][128];
    int n0 = blockIdx.x * NPB;
    int c = threadIdx.x;
    #pragma unroll
    for (int j = 0; j < NPB; j++) {
        int n = n0 + j;
        rows[j][c] = (n < N) ? in[(size_t)n * 128 + c] : 0.f;
    }
    __syncthreads();
    float acc[NPB];
    #pragma unroll
    for (int j = 0; j < NPB; j++) acc[j] = 0.f;
    for (int k = 0; k < 128; k++) {
        float wv = W2[k * 128 + c];
        #pragma unroll
        for (int j = 0; j < NPB; j++) acc[j] += rows[j][k] * wv;
    }
    float as = att_src[c], ad = att_dst[c];
    for (int j = 0; j < NPB; j++) {
        int n = n0 + j;
        if (n >= N) break;
        h[(size_t)n * 128 + c] = acc[j];
        float ps = acc[j] * as, pd = acc[j] * ad;
        #pragma unroll
        for (int off = 16; off >= 1; off >>= 1) {
            ps += __shfl_xor(ps, off, 64);
            pd += __shfl_xor(pd, off, 64);
        }
        if ((c & 31) == 0) {
            int head = c >> 5;
            asrc[n * 4 + head] = ps;
            adst[n * 4 + head] = pd;
        }
    }
}

extern "C" void kernel_launch(void* const* d_in, const int* in_sizes, int n_in,
                              void* d_out, int out_size, void* d_ws, size_t ws_size,
                              hipStream_t stream)
{
    const float* x   = (const float*)d_in[0];
    const int*   ei  = (const int*)  d_in[1];
    const float* W1  = (const float*)d_in[2];
    const float* as1 = (const float*)d_in[3];
    const float* ad1 = (const float*)d_in[4];
    const float* b1  = (const float*)d_in[5];
    const float* W2  = (const float*)d_in[6];
    const float* as2 = (const float*)d_in[7];
    const float* ad2 = (const float*)d_in[8];
    const float* b2  = (const float*)d_in[9];
    const float* Wl  = (const float*)d_in[10];
    const float* bl  = (const float*)d_in[11];
    float* out = (float*)d_out;

    int N  = in_sizes[0] / 8;
    int E  = in_sizes[1] / 2;
    int EN = E + N;
    int G  = (N + SCAN_B - 1) / SCAN_B;         // scan tiles (98 for N=100k)

    float* ws    = (float*)d_ws;
    float* A     = ws;                          // N*128: h1, then h2
    float* B     = A + (size_t)N * 128;         // N*128: out1 (= feat2 input)
    float* asrc  = B + (size_t)N * 128;         // N*4
    float* adst  = asrc + (size_t)N * 4;        // N*4
    int* cnt     = (int*)(adst + (size_t)N * 4);// N  (counts, then cursor)
    int* rowptr  = cnt + N;                     // N+1
    int* bsum    = rowptr + N + 1;              // G
    int* esrc    = bsum + G;                    // EN

    int eb = (EN + 255) / 256;
    int nb = (N + 3) / 4;                       // 4 waves/block, 1 wave/node

    // CSR build (shared by both layers)
    hipMemsetAsync(cnt, 0, (size_t)N * sizeof(int), stream);
    k_hist<<<eb, 256, 0, stream>>>(ei, E, EN, cnt);
    k_scanA<<<G, SCAN_B, 0, stream>>>(cnt, bsum, N);
    k_scanB<<<1, SCAN_B, 0, stream>>>(bsum, G);
    k_scanC<<<G, SCAN_B, 0, stream>>>(cnt, bsum, rowptr, N);
    k_scatter<<<eb, 256, 0, stream>>>(ei, E, EN, cnt, esrc);

    // Layer 1
    k_feat1<<<N, 128, 0, stream>>>(x, W1, as1, ad1, A, asrc, adst, N);
    k_agg1<<<nb, 256, 0, stream>>>(rowptr, esrc, A, asrc, adst, b1, B, N);

    // Layer 2
    k_feat2<<<(N + NPB - 1) / NPB, 128, 0, stream>>>(B, W2, as2, ad2, A, asrc, adst, N);
    k_agg2<<<nb, 256, 0, stream>>>(rowptr, esrc, A, asrc, adst, b2, Wl, bl, out, N);
}

// Round 4
// 554.921 us; speedup vs baseline: 10.9320x; 1.1889x over previous
//
#include <hip/hip_runtime.h>

#define NEG_SLOPE 0.2f
#define NPB 8
#define SCAN_B 1024

// K1: h = x @ W1  [N,128]; asrc[n,h] = <h[n,h,:], att_src[h,:]>; adst likewise.
__global__ __launch_bounds__(128) void k_feat1(
    const float* __restrict__ x, const float* __restrict__ W1,
    const float* __restrict__ att_src, const float* __restrict__ att_dst,
    float* __restrict__ h, float* __restrict__ asrc, float* __restrict__ adst, int N)
{
    int n = blockIdx.x;
    int c = threadIdx.x;            // 0..127, flat channel = head*32+cc
    const float* xr = x + (size_t)n * 8;
    float acc = 0.f;
    #pragma unroll
    for (int k = 0; k < 8; k++) acc += xr[k] * W1[k * 128 + c];
    h[(size_t)n * 128 + c] = acc;
    float ps = acc * att_src[c];
    float pd = acc * att_dst[c];
    #pragma unroll
    for (int off = 16; off >= 1; off >>= 1) {
        ps += __shfl_xor(ps, off, 64);
        pd += __shfl_xor(pd, off, 64);
    }
    if ((c & 31) == 0) {
        int head = c >> 5;
        asrc[n * 4 + head] = ps;
        adst[n * 4 + head] = pd;
    }
}

// CSR step 1: in-degree histogram; the returned old count IS the edge's
// within-bucket rank -> stored coalesced, so placement needs no atomics.
__global__ __launch_bounds__(256) void k_rank(
    const int* __restrict__ ei, int E, int EN,
    int* __restrict__ cnt, int* __restrict__ rank)
{
    int e = blockIdx.x * 256 + threadIdx.x;
    if (e >= EN) return;
    int dst = (e < E) ? ei[E + e] : (e - E);
    rank[e] = atomicAdd(&cnt[dst], 1);
}

// Scan phase A: per-1024-tile sums.
__global__ __launch_bounds__(SCAN_B) void k_scanA(
    const int* __restrict__ cnt, int* __restrict__ bsum, int N)
{
    __shared__ int red[SCAN_B];
    int t = threadIdx.x;
    int i = blockIdx.x * SCAN_B + t;
    red[t] = (i < N) ? cnt[i] : 0;
    __syncthreads();
    #pragma unroll
    for (int off = SCAN_B / 2; off > 0; off >>= 1) {
        if (t < off) red[t] += red[t + off];
        __syncthreads();
    }
    if (t == 0) bsum[blockIdx.x] = red[0];
}

// Scan phase B: exclusive scan of bsum[G] in one block (G <= 1024).
__global__ __launch_bounds__(SCAN_B) void k_scanB(int* __restrict__ bsum, int G)
{
    __shared__ int s[SCAN_B];
    int t = threadIdx.x;
    int v = (t < G) ? bsum[t] : 0;
    s[t] = v;
    __syncthreads();
    for (int off = 1; off < SCAN_B; off <<= 1) {
        int u = (t >= off) ? s[t - off] : 0;
        __syncthreads();
        s[t] += u;
        __syncthreads();
    }
    if (t < G) bsum[t] = s[t] - v;      // exclusive
}

// Scan phase C: intra-tile exclusive scan + block offset -> rowptr[N+1].
__global__ __launch_bounds__(SCAN_B) void k_scanC(
    const int* __restrict__ cnt, const int* __restrict__ bsum,
    int* __restrict__ rowptr, int N)
{
    __shared__ int s[SCAN_B];
    int t = threadIdx.x;
    int i = blockIdx.x * SCAN_B + t;
    int v = (i < N) ? cnt[i] : 0;
    s[t] = v;
    __syncthreads();
    for (int off = 1; off < SCAN_B; off <<= 1) {
        int u = (t >= off) ? s[t - off] : 0;
        __syncthreads();
        s[t] += u;
        __syncthreads();
    }
    int excl = s[t] - v + bsum[blockIdx.x];
    if (i < N) {
        rowptr[i] = excl;
        if (i == N - 1) rowptr[N] = excl + v;
    }
}

// CSR step 3: atomic-free placement using precomputed ranks.
__global__ __launch_bounds__(256) void k_place(
    const int* __restrict__ ei, int E, int EN,
    const int* __restrict__ rowptr, const int* __restrict__ rank,
    int* __restrict__ esrc)
{
    int e = blockIdx.x * 256 + threadIdx.x;
    if (e >= EN) return;
    int src, dst;
    if (e < E) { src = ei[e]; dst = ei[E + e]; }
    else       { src = dst = e - E; }
    esrc[rowptr[dst] + rank[e]] = src;
}

// Core: one wave per dst node. Lane owns channels {2*lane, 2*lane+1}, both in
// head (lane>>4): ONE attention weight per lane per edge.
__device__ __forceinline__ void agg_core(
    int n, int lane,
    const int* __restrict__ rowptr, const int* __restrict__ esrc,
    const float* __restrict__ h, const float* __restrict__ asrc,
    const float* __restrict__ adst,
    float& ax, float& ay, float& d)
{
    int head = lane >> 4;
    float ad = adst[n * 4 + head];
    ax = ay = d = 0.f;
    int beg = rowptr[n], end = rowptr[n + 1];
    #pragma unroll 4
    for (int j = beg; j < end; j++) {
        int src = esrc[j];                          // wave-uniform
        float a = asrc[src * 4 + head] + ad;        // 16B broadcast across wave
        a = a > 0.f ? a : NEG_SLOPE * a;
        float w = __expf(a);                        // |a| small: no max-sub needed
        const float2 hv = *reinterpret_cast<const float2*>(
            h + (size_t)src * 128 + lane * 2);
        ax = fmaf(w, hv.x, ax);
        ay = fmaf(w, hv.y, ay);
        d += w;
    }
}

// Layer-1 aggregate + fused epilogue: out = relu(acc/denom + bias1).
__global__ __launch_bounds__(256) void k_agg1(
    const int* __restrict__ rowptr, const int* __restrict__ esrc,
    const float* __restrict__ h, const float* __restrict__ asrc,
    const float* __restrict__ adst, const float* __restrict__ bias,
    float* __restrict__ outp, int N)
{
    int wave = (blockIdx.x * 256 + threadIdx.x) >> 6;
    if (wave >= N) return;
    int lane = threadIdx.x & 63;
    float ax, ay, d;
    agg_core(wave, lane, rowptr, esrc, h, asrc, adst, ax, ay, d);
    float inv = 1.f / d;
    const float2 bv = *reinterpret_cast<const float2*>(bias + lane * 2);
    float v0 = ax * inv + bv.x;
    float v1 = ay * inv + bv.y;
    float2 o;
    o.x = v0 > 0.f ? v0 : 0.f;
    o.y = v1 > 0.f ? v1 : 0.f;
    *reinterpret_cast<float2*>(outp + (size_t)wave * 128 + lane * 2) = o;
}

// Layer-2 aggregate + fused final: mean over heads, +bias2, relu, dot W_lin.
__global__ __launch_bounds__(256) void k_agg2(
    const int* __restrict__ rowptr, const int* __restrict__ esrc,
    const float* __restrict__ h, const float* __restrict__ asrc,
    const float* __restrict__ adst, const float* __restrict__ bias2,
    const float* __restrict__ Wlin, const float* __restrict__ blin,
    float* __restrict__ out, int N)
{
    int wave = (blockIdx.x * 256 + threadIdx.x) >> 6;
    if (wave >= N) return;
    int lane = threadIdx.x & 63;
    float ax, ay, d;
    agg_core(wave, lane, rowptr, esrc, h, asrc, adst, ax, ay, d);
    float inv = 1.f / d;
    float vx = ax * inv, vy = ay * inv;
    // sum the 4 head groups (lanes differing by 16/32 hold same cc, other heads)
    vx += __shfl_xor(vx, 16, 64);
    vx += __shfl_xor(vx, 32, 64);
    vy += __shfl_xor(vy, 16, 64);
    vy += __shfl_xor(vy, 32, 64);
    int cc = (lane & 15) * 2;
    float m0 = 0.25f * vx + bias2[cc];
    float m1 = 0.25f * vy + bias2[cc + 1];
    float y0 = m0 > 0.f ? m0 : 0.f;
    float y1 = m1 > 0.f ? m1 : 0.f;
    float t = y0 * Wlin[cc] + y1 * Wlin[cc + 1];
    #pragma unroll
    for (int off = 8; off >= 1; off >>= 1) t += __shfl_xor(t, off, 64);
    if (lane == 0) out[wave] = t + blin[0];
}

// h2 = out1 @ W2 (128x128) + asrc2/adst2. NPB nodes per block share W2 reads.
__global__ __launch_bounds__(128) void k_feat2(
    const float* __restrict__ in, const float* __restrict__ W2,
    const float* __restrict__ att_src, const float* __restrict__ att_dst,
    float* __restrict__ h, float* __restrict__ asrc, float* __restrict__ adst, int N)
{
    __shared__ float rows[NPB][128];
    int n0 = blockIdx.x * NPB;
    int c = threadIdx.x;
    #pragma unroll
    for (int j = 0; j < NPB; j++) {
        int n = n0 + j;
        rows[j][c] = (n < N) ? in[(size_t)n * 128 + c] : 0.f;
    }
    __syncthreads();
    float acc[NPB];
    #pragma unroll
    for (int j = 0; j < NPB; j++) acc[j] = 0.f;
    for (int k = 0; k < 128; k++) {
        float wv = W2[k * 128 + c];
        #pragma unroll
        for (int j = 0; j < NPB; j++) acc[j] += rows[j][k] * wv;
    }
    float as = att_src[c], ad = att_dst[c];
    for (int j = 0; j < NPB; j++) {
        int n = n0 + j;
        if (n >= N) break;
        h[(size_t)n * 128 + c] = acc[j];
        float ps = acc[j] * as, pd = acc[j] * ad;
        #pragma unroll
        for (int off = 16; off >= 1; off >>= 1) {
            ps += __shfl_xor(ps, off, 64);
            pd += __shfl_xor(pd, off, 64);
        }
        if ((c & 31) == 0) {
            int head = c >> 5;
            asrc[n * 4 + head] = ps;
            adst[n * 4 + head] = pd;
        }
    }
}

extern "C" void kernel_launch(void* const* d_in, const int* in_sizes, int n_in,
                              void* d_out, int out_size, void* d_ws, size_t ws_size,
                              hipStream_t stream)
{
    const float* x   = (const float*)d_in[0];
    const int*   ei  = (const int*)  d_in[1];
    const float* W1  = (const float*)d_in[2];
    const float* as1 = (const float*)d_in[3];
    const float* ad1 = (const float*)d_in[4];
    const float* b1  = (const float*)d_in[5];
    const float* W2  = (const float*)d_in[6];
    const float* as2 = (const float*)d_in[7];
    const float* ad2 = (const float*)d_in[8];
    const float* b2  = (const float*)d_in[9];
    const float* Wl  = (const float*)d_in[10];
    const float* bl  = (const float*)d_in[11];
    float* out = (float*)d_out;

    int N  = in_sizes[0] / 8;
    int E  = in_sizes[1] / 2;
    int EN = E + N;
    int G  = (N + SCAN_B - 1) / SCAN_B;         // scan tiles (98 for N=100k)

    float* ws    = (float*)d_ws;
    float* A     = ws;                          // N*128: h1, then h2
    float* B     = A + (size_t)N * 128;         // N*128: out1; rank aliases this
    float* asrc  = B + (size_t)N * 128;         // N*4
    float* adst  = asrc + (size_t)N * 4;        // N*4
    int* cnt     = (int*)(adst + (size_t)N * 4);// N
    int* rowptr  = cnt + N;                     // N+1
    int* bsum    = rowptr + N + 1;              // G
    int* esrc    = bsum + G;                    // EN
    int* rank    = (int*)B;                     // EN ints, dead before k_agg1

    int eb = (EN + 255) / 256;
    int nb = (N + 3) / 4;                       // 4 waves/block, 1 wave/node

    // CSR build (shared by both layers); rank pass reuses the histogram atomics.
    hipMemsetAsync(cnt, 0, (size_t)N * sizeof(int), stream);
    k_rank<<<eb, 256, 0, stream>>>(ei, E, EN, cnt, rank);
    k_scanA<<<G, SCAN_B, 0, stream>>>(cnt, bsum, N);
    k_scanB<<<1, SCAN_B, 0, stream>>>(bsum, G);
    k_scanC<<<G, SCAN_B, 0, stream>>>(cnt, bsum, rowptr, N);
    k_place<<<eb, 256, 0, stream>>>(ei, E, EN, rowptr, rank, esrc);

    // Layer 1
    k_feat1<<<N, 128, 0, stream>>>(x, W1, as1, ad1, A, asrc, adst, N);
    k_agg1<<<nb, 256, 0, stream>>>(rowptr, esrc, A, asrc, adst, b1, B, N);

    // Layer 2
    k_feat2<<<(N + NPB - 1) / NPB, 128, 0, stream>>>(B, W2, as2, ad2, A, asrc, adst, N);
    k_agg2<<<nb, 256, 0, stream>>>(rowptr, esrc, A, asrc, adst, b2, Wl, bl, out, N);
}

// Round 5
// 465.636 us; speedup vs baseline: 13.0282x; 1.1917x over previous
//
#include <hip/hip_runtime.h>

#define NEG_SLOPE 0.2f
#define NPB 8
#define SCAN_B 1024

// fp32 -> bf16 with round-to-nearest-even (bit trick; no NaN inputs here).
__device__ __forceinline__ unsigned short f2b(float f) {
    unsigned int u = __float_as_uint(f);
    u += 0x7FFFu + ((u >> 16) & 1u);
    return (unsigned short)(u >> 16);
}

// K1: h = bf16(x @ W1) [N,128]; asrc/adst from the fp32 values (exact scores).
__global__ __launch_bounds__(128) void k_feat1(
    const float* __restrict__ x, const float* __restrict__ W1,
    const float* __restrict__ att_src, const float* __restrict__ att_dst,
    unsigned short* __restrict__ h, float* __restrict__ asrc,
    float* __restrict__ adst, int N)
{
    int n = blockIdx.x;
    int c = threadIdx.x;            // 0..127, flat channel = head*32+cc
    const float* xr = x + (size_t)n * 8;
    float acc = 0.f;
    #pragma unroll
    for (int k = 0; k < 8; k++) acc += xr[k] * W1[k * 128 + c];
    h[(size_t)n * 128 + c] = f2b(acc);
    float ps = acc * att_src[c];
    float pd = acc * att_dst[c];
    #pragma unroll
    for (int off = 16; off >= 1; off >>= 1) {
        ps += __shfl_xor(ps, off, 64);
        pd += __shfl_xor(pd, off, 64);
    }
    if ((c & 31) == 0) {
        int head = c >> 5;
        asrc[n * 4 + head] = ps;
        adst[n * 4 + head] = pd;
    }
}

// CSR step 1: histogram; returned old count IS the edge's within-bucket rank.
__global__ __launch_bounds__(256) void k_rank(
    const int* __restrict__ ei, int E, int EN,
    int* __restrict__ cnt, int* __restrict__ rank)
{
    int e = blockIdx.x * 256 + threadIdx.x;
    if (e >= EN) return;
    int dst = (e < E) ? ei[E + e] : (e - E);
    rank[e] = atomicAdd(&cnt[dst], 1);
}

// Scan phase A: per-1024-tile sums.
__global__ __launch_bounds__(SCAN_B) void k_scanA(
    const int* __restrict__ cnt, int* __restrict__ bsum, int N)
{
    __shared__ int red[SCAN_B];
    int t = threadIdx.x;
    int i = blockIdx.x * SCAN_B + t;
    red[t] = (i < N) ? cnt[i] : 0;
    __syncthreads();
    #pragma unroll
    for (int off = SCAN_B / 2; off > 0; off >>= 1) {
        if (t < off) red[t] += red[t + off];
        __syncthreads();
    }
    if (t == 0) bsum[blockIdx.x] = red[0];
}

// Scan phase B: exclusive scan of bsum[G] in one block (G <= 1024).
__global__ __launch_bounds__(SCAN_B) void k_scanB(int* __restrict__ bsum, int G)
{
    __shared__ int s[SCAN_B];
    int t = threadIdx.x;
    int v = (t < G) ? bsum[t] : 0;
    s[t] = v;
    __syncthreads();
    for (int off = 1; off < SCAN_B; off <<= 1) {
        int u = (t >= off) ? s[t - off] : 0;
        __syncthreads();
        s[t] += u;
        __syncthreads();
    }
    if (t < G) bsum[t] = s[t] - v;      // exclusive
}

// Scan phase C: intra-tile exclusive scan + block offset -> rowptr[N+1].
__global__ __launch_bounds__(SCAN_B) void k_scanC(
    const int* __restrict__ cnt, const int* __restrict__ bsum,
    int* __restrict__ rowptr, int N)
{
    __shared__ int s[SCAN_B];
    int t = threadIdx.x;
    int i = blockIdx.x * SCAN_B + t;
    int v = (i < N) ? cnt[i] : 0;
    s[t] = v;
    __syncthreads();
    for (int off = 1; off < SCAN_B; off <<= 1) {
        int u = (t >= off) ? s[t - off] : 0;
        __syncthreads();
        s[t] += u;
        __syncthreads();
    }
    int excl = s[t] - v + bsum[blockIdx.x];
    if (i < N) {
        rowptr[i] = excl;
        if (i == N - 1) rowptr[N] = excl + v;
    }
}

// CSR step 3: atomic-free placement using precomputed ranks.
__global__ __launch_bounds__(256) void k_place(
    const int* __restrict__ ei, int E, int EN,
    const int* __restrict__ rowptr, const int* __restrict__ rank,
    int* __restrict__ esrc)
{
    int e = blockIdx.x * 256 + threadIdx.x;
    if (e >= EN) return;
    int src, dst;
    if (e < E) { src = ei[e]; dst = ei[E + e]; }
    else       { src = dst = e - E; }
    esrc[rowptr[dst] + rank[e]] = src;
}

// Core: one wave per dst node. Lane owns channels {2*lane, 2*lane+1} (head
// lane>>4): one attention weight + ONE dword (bf16x2) h-load per lane per edge.
__device__ __forceinline__ void agg_core(
    int n, int lane,
    const int* __restrict__ rowptr, const int* __restrict__ esrc,
    const unsigned int* __restrict__ h /* bf16x2, 64 dwords per node */,
    const float* __restrict__ asrc, const float* __restrict__ adst,
    float& ax, float& ay, float& d)
{
    int head = lane >> 4;
    float ad = adst[n * 4 + head];
    ax = ay = d = 0.f;
    int beg = rowptr[n], end = rowptr[n + 1];
    #pragma unroll 4
    for (int j = beg; j < end; j++) {
        int src = esrc[j];                          // wave-uniform
        float a = asrc[src * 4 + head] + ad;
        a = a > 0.f ? a : NEG_SLOPE * a;
        float w = __expf(a);                        // |a| small: no max-sub needed
        unsigned int u = h[(size_t)src * 64 + lane];
        float lo = __uint_as_float(u << 16);        // channel 2*lane
        float hi = __uint_as_float(u & 0xFFFF0000u);// channel 2*lane+1
        ax = fmaf(w, lo, ax);
        ay = fmaf(w, hi, ay);
        d += w;
    }
}

// Layer-1 aggregate + fused epilogue: out1 = relu(acc/denom + bias1)  (fp32).
__global__ __launch_bounds__(256) void k_agg1(
    const int* __restrict__ rowptr, const int* __restrict__ esrc,
    const unsigned int* __restrict__ h, const float* __restrict__ asrc,
    const float* __restrict__ adst, const float* __restrict__ bias,
    float* __restrict__ outp, int N)
{
    int wave = (blockIdx.x * 256 + threadIdx.x) >> 6;
    if (wave >= N) return;
    int lane = threadIdx.x & 63;
    float ax, ay, d;
    agg_core(wave, lane, rowptr, esrc, h, asrc, adst, ax, ay, d);
    float inv = 1.f / d;
    const float2 bv = *reinterpret_cast<const float2*>(bias + lane * 2);
    float v0 = ax * inv + bv.x;
    float v1 = ay * inv + bv.y;
    float2 o;
    o.x = v0 > 0.f ? v0 : 0.f;
    o.y = v1 > 0.f ? v1 : 0.f;
    *reinterpret_cast<float2*>(outp + (size_t)wave * 128 + lane * 2) = o;
}

// Layer-2 aggregate + fused final: mean over heads, +bias2, relu, dot W_lin.
__global__ __launch_bounds__(256) void k_agg2(
    const int* __restrict__ rowptr, const int* __restrict__ esrc,
    const unsigned int* __restrict__ h, const float* __restrict__ asrc,
    const float* __restrict__ adst, const float* __restrict__ bias2,
    const float* __restrict__ Wlin, const float* __restrict__ blin,
    float* __restrict__ out, int N)
{
    int wave = (blockIdx.x * 256 + threadIdx.x) >> 6;
    if (wave >= N) return;
    int lane = threadIdx.x & 63;
    float ax, ay, d;
    agg_core(wave, lane, rowptr, esrc, h, asrc, adst, ax, ay, d);
    float inv = 1.f / d;
    float vx = ax * inv, vy = ay * inv;
    // sum the 4 head groups (lanes differing by 16/32 hold same cc, other heads)
    vx += __shfl_xor(vx, 16, 64);
    vx += __shfl_xor(vx, 32, 64);
    vy += __shfl_xor(vy, 16, 64);
    vy += __shfl_xor(vy, 32, 64);
    int cc = (lane & 15) * 2;
    float m0 = 0.25f * vx + bias2[cc];
    float m1 = 0.25f * vy + bias2[cc + 1];
    float y0 = m0 > 0.f ? m0 : 0.f;
    float y1 = m1 > 0.f ? m1 : 0.f;
    float t = y0 * Wlin[cc] + y1 * Wlin[cc + 1];
    #pragma unroll
    for (int off = 8; off >= 1; off >>= 1) t += __shfl_xor(t, off, 64);
    if (lane == 0) out[wave] = t + blin[0];
}

// h2 = bf16(out1 @ W2) + asrc2/adst2 (scores from fp32 accs, exact).
__global__ __launch_bounds__(128) void k_feat2(
    const float* __restrict__ in, const float* __restrict__ W2,
    const float* __restrict__ att_src, const float* __restrict__ att_dst,
    unsigned short* __restrict__ h, float* __restrict__ asrc,
    float* __restrict__ adst, int N)
{
    __shared__ float rows[NPB][128];
    int n0 = blockIdx.x * NPB;
    int c = threadIdx.x;
    #pragma unroll
    for (int j = 0; j < NPB; j++) {
        int n = n0 + j;
        rows[j][c] = (n < N) ? in[(size_t)n * 128 + c] : 0.f;
    }
    __syncthreads();
    float acc[NPB];
    #pragma unroll
    for (int j = 0; j < NPB; j++) acc[j] = 0.f;
    for (int k = 0; k < 128; k++) {
        float wv = W2[k * 128 + c];
        #pragma unroll
        for (int j = 0; j < NPB; j++) acc[j] += rows[j][k] * wv;
    }
    float as = att_src[c], ad = att_dst[c];
    for (int j = 0; j < NPB; j++) {
        int n = n0 + j;
        if (n >= N) break;
        h[(size_t)n * 128 + c] = f2b(acc[j]);
        float ps = acc[j] * as, pd = acc[j] * ad;
        #pragma unroll
        for (int off = 16; off >= 1; off >>= 1) {
            ps += __shfl_xor(ps, off, 64);
            pd += __shfl_xor(pd, off, 64);
        }
        if ((c & 31) == 0) {
            int head = c >> 5;
            asrc[n * 4 + head] = ps;
            adst[n * 4 + head] = pd;
        }
    }
}

extern "C" void kernel_launch(void* const* d_in, const int* in_sizes, int n_in,
                              void* d_out, int out_size, void* d_ws, size_t ws_size,
                              hipStream_t stream)
{
    const float* x   = (const float*)d_in[0];
    const int*   ei  = (const int*)  d_in[1];
    const float* W1  = (const float*)d_in[2];
    const float* as1 = (const float*)d_in[3];
    const float* ad1 = (const float*)d_in[4];
    const float* b1  = (const float*)d_in[5];
    const float* W2  = (const float*)d_in[6];
    const float* as2 = (const float*)d_in[7];
    const float* ad2 = (const float*)d_in[8];
    const float* b2  = (const float*)d_in[9];
    const float* Wl  = (const float*)d_in[10];
    const float* bl  = (const float*)d_in[11];
    float* out = (float*)d_out;

    int N  = in_sizes[0] / 8;
    int E  = in_sizes[1] / 2;
    int EN = E + N;
    int G  = (N + SCAN_B - 1) / SCAN_B;         // scan tiles (98 for N=100k)

    float* ws    = (float*)d_ws;
    unsigned short* A = (unsigned short*)ws;    // N*128 bf16: h1, then h2
    float* B     = ws + (size_t)N * 64;         // N*128 fp32: out1; rank aliases
    float* asrc  = B + (size_t)N * 128;         // N*4
    float* adst  = asrc + (size_t)N * 4;        // N*4
    int* cnt     = (int*)(adst + (size_t)N * 4);// N
    int* rowptr  = cnt + N;                     // N+1
    int* bsum    = rowptr + N + 1;              // G
    int* esrc    = bsum + G;                    // EN
    int* rank    = (int*)B;                     // EN ints, dead before k_agg1

    int eb = (EN + 255) / 256;
    int nb = (N + 3) / 4;                       // 4 waves/block, 1 wave/node

    // CSR build (shared by both layers)
    hipMemsetAsync(cnt, 0, (size_t)N * sizeof(int), stream);
    k_rank<<<eb, 256, 0, stream>>>(ei, E, EN, cnt, rank);
    k_scanA<<<G, SCAN_B, 0, stream>>>(cnt, bsum, N);
    k_scanB<<<1, SCAN_B, 0, stream>>>(bsum, G);
    k_scanC<<<G, SCAN_B, 0, stream>>>(cnt, bsum, rowptr, N);
    k_place<<<eb, 256, 0, stream>>>(ei, E, EN, rowptr, rank, esrc);

    // Layer 1
    k_feat1<<<N, 128, 0, stream>>>(x, W1, as1, ad1, A, asrc, adst, N);
    k_agg1<<<nb, 256, 0, stream>>>(rowptr, esrc, (const unsigned int*)A,
                                   asrc, adst, b1, B, N);

    // Layer 2
    k_feat2<<<(N + NPB - 1) / NPB, 128, 0, stream>>>(B, W2, as2, ad2, A, asrc, adst, N);
    k_agg2<<<nb, 256, 0, stream>>>(rowptr, esrc, (const unsigned int*)A,
                                   asrc, adst, b2, Wl, bl, out, N);
}

// Round 6
// 404.470 us; speedup vs baseline: 14.9984x; 1.1512x over previous
//
#include <hip/hip_runtime.h>

#define NEG_SLOPE 0.2f
#define SCAN_B 1024

typedef __attribute__((ext_vector_type(8))) short bf16x8;   // MFMA A/B frag
typedef __attribute__((ext_vector_type(4))) float f32x4;    // MFMA C/D frag

// fp32 -> bf16 round-to-nearest-even (no NaN inputs here).
__device__ __forceinline__ unsigned short f2b(float f) {
    unsigned int u = __float_as_uint(f);
    u += 0x7FFFu + ((u >> 16) & 1u);
    return (unsigned short)(u >> 16);
}

// K1: h = bf16(x @ W1) [N,128]; asrc/adst from the fp32 values (exact scores).
__global__ __launch_bounds__(128) void k_feat1(
    const float* __restrict__ x, const float* __restrict__ W1,
    const float* __restrict__ att_src, const float* __restrict__ att_dst,
    unsigned short* __restrict__ h, float* __restrict__ asrc,
    float* __restrict__ adst, int N)
{
    int n = blockIdx.x;
    int c = threadIdx.x;            // 0..127, flat channel = head*32+cc
    const float* xr = x + (size_t)n * 8;
    float acc = 0.f;
    #pragma unroll
    for (int k = 0; k < 8; k++) acc += xr[k] * W1[k * 128 + c];
    h[(size_t)n * 128 + c] = f2b(acc);
    float ps = acc * att_src[c];
    float pd = acc * att_dst[c];
    #pragma unroll
    for (int off = 16; off >= 1; off >>= 1) {
        ps += __shfl_xor(ps, off, 64);
        pd += __shfl_xor(pd, off, 64);
    }
    if ((c & 31) == 0) {
        int head = c >> 5;
        asrc[n * 4 + head] = ps;
        adst[n * 4 + head] = pd;
    }
}

// CSR step 1: histogram; returned old count IS the edge's within-bucket rank.
__global__ __launch_bounds__(256) void k_rank(
    const int* __restrict__ ei, int E, int EN,
    int* __restrict__ cnt, int* __restrict__ rank)
{
    int e = blockIdx.x * 256 + threadIdx.x;
    if (e >= EN) return;
    int dst = (e < E) ? ei[E + e] : (e - E);
    rank[e] = atomicAdd(&cnt[dst], 1);
}

// Scan phase A: per-1024-tile sums.
__global__ __launch_bounds__(SCAN_B) void k_scanA(
    const int* __restrict__ cnt, int* __restrict__ bsum, int N)
{
    __shared__ int red[SCAN_B];
    int t = threadIdx.x;
    int i = blockIdx.x * SCAN_B + t;
    red[t] = (i < N) ? cnt[i] : 0;
    __syncthreads();
    #pragma unroll
    for (int off = SCAN_B / 2; off > 0; off >>= 1) {
        if (t < off) red[t] += red[t + off];
        __syncthreads();
    }
    if (t == 0) bsum[blockIdx.x] = red[0];
}

// Scan phase B: exclusive scan of bsum[G] in one block (G <= 1024).
__global__ __launch_bounds__(SCAN_B) void k_scanB(int* __restrict__ bsum, int G)
{
    __shared__ int s[SCAN_B];
    int t = threadIdx.x;
    int v = (t < G) ? bsum[t] : 0;
    s[t] = v;
    __syncthreads();
    for (int off = 1; off < SCAN_B; off <<= 1) {
        int u = (t >= off) ? s[t - off] : 0;
        __syncthreads();
        s[t] += u;
        __syncthreads();
    }
    if (t < G) bsum[t] = s[t] - v;      // exclusive
}

// Scan phase C: intra-tile exclusive scan + block offset -> rowptr[N+1].
__global__ __launch_bounds__(SCAN_B) void k_scanC(
    const int* __restrict__ cnt, const int* __restrict__ bsum,
    int* __restrict__ rowptr, int N)
{
    __shared__ int s[SCAN_B];
    int t = threadIdx.x;
    int i = blockIdx.x * SCAN_B + t;
    int v = (i < N) ? cnt[i] : 0;
    s[t] = v;
    __syncthreads();
    for (int off = 1; off < SCAN_B; off <<= 1) {
        int u = (t >= off) ? s[t - off] : 0;
        __syncthreads();
        s[t] += u;
        __syncthreads();
    }
    int excl = s[t] - v + bsum[blockIdx.x];
    if (i < N) {
        rowptr[i] = excl;
        if (i == N - 1) rowptr[N] = excl + v;
    }
}

// CSR step 3: atomic-free placement using precomputed ranks.
__global__ __launch_bounds__(256) void k_place(
    const int* __restrict__ ei, int E, int EN,
    const int* __restrict__ rowptr, const int* __restrict__ rank,
    int* __restrict__ esrc)
{
    int e = blockIdx.x * 256 + threadIdx.x;
    if (e >= EN) return;
    int src, dst;
    if (e < E) { src = ei[e]; dst = ei[E + e]; }
    else       { src = dst = e - E; }
    esrc[rowptr[dst] + rank[e]] = src;
}

// Core: one wave per dst node. Lane owns channels {2*lane, 2*lane+1} (head
// lane>>4): one attention weight + ONE dword (bf16x2) h-load per lane per edge.
__device__ __forceinline__ void agg_core(
    int n, int lane,
    const int* __restrict__ rowptr, const int* __restrict__ esrc,
    const unsigned int* __restrict__ h /* bf16x2, 64 dwords per node */,
    const float* __restrict__ asrc, const float* __restrict__ adst,
    float& ax, float& ay, float& d)
{
    int head = lane >> 4;
    float ad = adst[n * 4 + head];
    ax = ay = d = 0.f;
    int beg = rowptr[n], end = rowptr[n + 1];
    #pragma unroll 4
    for (int j = beg; j < end; j++) {
        int src = esrc[j];                          // wave-uniform
        float a = asrc[src * 4 + head] + ad;
        a = a > 0.f ? a : NEG_SLOPE * a;
        float w = __expf(a);                        // |a| small: no max-sub needed
        unsigned int u = h[(size_t)src * 64 + lane];
        float lo = __uint_as_float(u << 16);        // channel 2*lane
        float hi = __uint_as_float(u & 0xFFFF0000u);// channel 2*lane+1
        ax = fmaf(w, lo, ax);
        ay = fmaf(w, hi, ay);
        d += w;
    }
}

// Layer-1 aggregate + fused epilogue: out1 = bf16(relu(acc/denom + bias1)),
// stored packed (feat2's MFMA consumes bf16 A-operand directly).
__global__ __launch_bounds__(256) void k_agg1(
    const int* __restrict__ rowptr, const int* __restrict__ esrc,
    const unsigned int* __restrict__ h, const float* __restrict__ asrc,
    const float* __restrict__ adst, const float* __restrict__ bias,
    unsigned int* __restrict__ out1b, int N)
{
    int wave = (blockIdx.x * 256 + threadIdx.x) >> 6;
    if (wave >= N) return;
    int lane = threadIdx.x & 63;
    float ax, ay, d;
    agg_core(wave, lane, rowptr, esrc, h, asrc, adst, ax, ay, d);
    float inv = 1.f / d;
    const float2 bv = *reinterpret_cast<const float2*>(bias + lane * 2);
    float v0 = ax * inv + bv.x;
    float v1 = ay * inv + bv.y;
    v0 = v0 > 0.f ? v0 : 0.f;
    v1 = v1 > 0.f ? v1 : 0.f;
    unsigned int pk = ((unsigned int)f2b(v1) << 16) | (unsigned int)f2b(v0);
    out1b[(size_t)wave * 64 + lane] = pk;
}

// Layer-2 aggregate + fused final: mean over heads, +bias2, relu, dot W_lin.
__global__ __launch_bounds__(256) void k_agg2(
    const int* __restrict__ rowptr, const int* __restrict__ esrc,
    const unsigned int* __restrict__ h, const float* __restrict__ asrc,
    const float* __restrict__ adst, const float* __restrict__ bias2,
    const float* __restrict__ Wlin, const float* __restrict__ blin,
    float* __restrict__ out, int N)
{
    int wave = (blockIdx.x * 256 + threadIdx.x) >> 6;
    if (wave >= N) return;
    int lane = threadIdx.x & 63;
    float ax, ay, d;
    agg_core(wave, lane, rowptr, esrc, h, asrc, adst, ax, ay, d);
    float inv = 1.f / d;
    float vx = ax * inv, vy = ay * inv;
    vx += __shfl_xor(vx, 16, 64);
    vx += __shfl_xor(vx, 32, 64);
    vy += __shfl_xor(vy, 16, 64);
    vy += __shfl_xor(vy, 32, 64);
    int cc = (lane & 15) * 2;
    float m0 = 0.25f * vx + bias2[cc];
    float m1 = 0.25f * vy + bias2[cc + 1];
    float y0 = m0 > 0.f ? m0 : 0.f;
    float y1 = m1 > 0.f ? m1 : 0.f;
    float t = y0 * Wlin[cc] + y1 * Wlin[cc + 1];
    #pragma unroll
    for (int off = 8; off >= 1; off >>= 1) t += __shfl_xor(t, off, 64);
    if (lane == 0) out[wave] = t + blin[0];
}

// Pack W2 (fp32 [128][128], k-major) into bf16 B-fragment layout:
// W2p[((tile_n*4 + kc)*64 + lane)*8 + j] = W2[kc*32 + (lane>>4)*8 + j][tile_n*16 + (lane&15)]
__global__ __launch_bounds__(256) void k_packW2(
    const float* __restrict__ W2, unsigned short* __restrict__ W2p)
{
    int w = threadIdx.x >> 6, lane = threadIdx.x & 63;
    int quad = lane >> 4, lanelo = lane & 15;
    int tile_n = blockIdx.x;                    // 0..7
    size_t base = (((size_t)tile_n * 4 + w) * 64 + lane) * 8;
    #pragma unroll
    for (int j = 0; j < 8; j++) {
        int k = w * 32 + quad * 8 + j;
        int n = tile_n * 16 + lanelo;
        W2p[base + j] = f2b(W2[k * 128 + n]);
    }
}

// h2 = bf16(out1 @ W2) via MFMA + fused score computation.
// Block = 4 waves = 32 nodes x 128 cols; wave w covers cols [w*32, w*32+32) = head w.
__global__ __launch_bounds__(256) void k_feat2(
    const unsigned short* __restrict__ in_b,   // out1 bf16 [N][128]
    const unsigned short* __restrict__ W2p,    // packed B-fragments
    const float* __restrict__ att_src, const float* __restrict__ att_dst,
    unsigned short* __restrict__ h, float* __restrict__ asrc,
    float* __restrict__ adst, int N)
{
    int w = threadIdx.x >> 6;
    int lane = threadIdx.x & 63;
    int quad = lane >> 4, lanelo = lane & 15;
    int mbase = blockIdx.x * 32;
    int wcb = w * 32;                           // wave col base == head w * 32

    f32x4 acc[2][2];                            // [row-tile][col-tile]
    #pragma unroll
    for (int rt = 0; rt < 2; rt++)
        #pragma unroll
        for (int ct = 0; ct < 2; ct++)
            acc[rt][ct] = (f32x4){0.f, 0.f, 0.f, 0.f};

    #pragma unroll
    for (int kc = 0; kc < 4; kc++) {
        bf16x8 a[2], b[2];
        #pragma unroll
        for (int rt = 0; rt < 2; rt++) {
            int node = mbase + rt * 16 + lanelo;        // A: m = lane&15
            if (node >= N) node = N - 1;                // clamp (guard at store)
            a[rt] = *reinterpret_cast<const bf16x8*>(
                in_b + (size_t)node * 128 + kc * 32 + quad * 8);
        }
        #pragma unroll
        for (int ct = 0; ct < 2; ct++) {
            int tile_n = w * 2 + ct;
            b[ct] = *reinterpret_cast<const bf16x8*>(
                W2p + (((size_t)tile_n * 4 + kc) * 64 + lane) * 8);
        }
        #pragma unroll
        for (int rt = 0; rt < 2; rt++)
            #pragma unroll
            for (int ct = 0; ct < 2; ct++)
                acc[rt][ct] = __builtin_amdgcn_mfma_f32_16x16x32_bf16(
                    a[rt], b[ct], acc[rt][ct], 0, 0, 0);
    }

    // Epilogue. C/D layout: n = lane&15, m = quad*4 + reg.
    float as_[2], ad_[2];
    #pragma unroll
    for (int ct = 0; ct < 2; ct++) {
        int col = wcb + ct * 16 + lanelo;
        as_[ct] = att_src[col];
        ad_[ct] = att_dst[col];
    }
    #pragma unroll
    for (int rt = 0; rt < 2; rt++) {
        #pragma unroll
        for (int reg = 0; reg < 4; reg++) {
            int node = mbase + rt * 16 + quad * 4 + reg;
            bool ok = node < N;
            float v0 = acc[rt][0][reg], v1 = acc[rt][1][reg];
            if (ok) {
                h[(size_t)node * 128 + wcb + lanelo]      = f2b(v0);
                h[(size_t)node * 128 + wcb + 16 + lanelo] = f2b(v1);
            }
            float ps = v0 * as_[0] + v1 * as_[1];
            float pd = v0 * ad_[0] + v1 * ad_[1];
            #pragma unroll
            for (int off = 8; off >= 1; off >>= 1) {
                ps += __shfl_xor(ps, off, 64);
                pd += __shfl_xor(pd, off, 64);
            }
            if (ok && lanelo == 0) {
                asrc[node * 4 + w] = ps;
                adst[node * 4 + w] = pd;
            }
        }
    }
}

extern "C" void kernel_launch(void* const* d_in, const int* in_sizes, int n_in,
                              void* d_out, int out_size, void* d_ws, size_t ws_size,
                              hipStream_t stream)
{
    const float* x   = (const float*)d_in[0];
    const int*   ei  = (const int*)  d_in[1];
    const float* W1  = (const float*)d_in[2];
    const float* as1 = (const float*)d_in[3];
    const float* ad1 = (const float*)d_in[4];
    const float* b1  = (const float*)d_in[5];
    const float* W2  = (const float*)d_in[6];
    const float* as2 = (const float*)d_in[7];
    const float* ad2 = (const float*)d_in[8];
    const float* b2  = (const float*)d_in[9];
    const float* Wl  = (const float*)d_in[10];
    const float* bl  = (const float*)d_in[11];
    float* out = (float*)d_out;

    int N  = in_sizes[0] / 8;
    int E  = in_sizes[1] / 2;
    int EN = E + N;
    int G  = (N + SCAN_B - 1) / SCAN_B;

    float* ws    = (float*)d_ws;
    unsigned short* A = (unsigned short*)ws;    // N*128 bf16: h1, then h2
    float* B     = ws + (size_t)N * 64;         // region: rank, then out1 bf16
    float* asrc  = B + (size_t)N * 128;         // N*4
    float* adst  = asrc + (size_t)N * 4;        // N*4
    int* cnt     = (int*)(adst + (size_t)N * 4);// N
    int* rowptr  = cnt + N;                     // N+1
    int* bsum    = rowptr + N + 1;              // G
    int* esrc    = bsum + G;                    // EN
    unsigned short* W2p = (unsigned short*)(esrc + EN);  // 16384 bf16
    int* rank    = (int*)B;                     // EN ints, dead before k_agg1
    unsigned int* out1b = (unsigned int*)B;     // N*64 dwords (bf16x2)

    int eb = (EN + 255) / 256;
    int nb = (N + 3) / 4;                       // 4 waves/block, 1 wave/node

    // CSR build (shared by both layers) + W2 pack
    hipMemsetAsync(cnt, 0, (size_t)N * sizeof(int), stream);
    k_rank<<<eb, 256, 0, stream>>>(ei, E, EN, cnt, rank);
    k_scanA<<<G, SCAN_B, 0, stream>>>(cnt, bsum, N);
    k_scanB<<<1, SCAN_B, 0, stream>>>(bsum, G);
    k_scanC<<<G, SCAN_B, 0, stream>>>(cnt, bsum, rowptr, N);
    k_place<<<eb, 256, 0, stream>>>(ei, E, EN, rowptr, rank, esrc);
    k_packW2<<<8, 256, 0, stream>>>(W2, W2p);

    // Layer 1
    k_feat1<<<N, 128, 0, stream>>>(x, W1, as1, ad1, A, asrc, adst, N);
    k_agg1<<<nb, 256, 0, stream>>>(rowptr, esrc, (const unsigned int*)A,
                                   asrc, adst, b1, out1b, N);

    // Layer 2
    k_feat2<<<(N + 31) / 32, 256, 0, stream>>>((const unsigned short*)out1b, W2p,
                                               as2, ad2, A, asrc, adst, N);
    k_agg2<<<nb, 256, 0, stream>>>(rowptr, esrc, (const unsigned int*)A,
                                   asrc, adst, b2, Wl, bl, out, N);
}